// Round 10
// baseline (346.330 us; speedup 1.0000x reference)
//
#include <hip/hip_runtime.h>
#include <cmath>

// ReadUnit, MFMA version. B=16, K=8192, D=128.
//  Im = m_prev@Wim+bim                      [B,D]    (prep kernel)
//  I  = (know@Wik+bik)*Im                   [B,K,D]  stage 1 (MFMA)
//  cI = c_cur*([I|know]@Wid+bid)            [B,K,D]  stage 2 (MFMA)
//  ra = cI@Wra+bra                          [B,K,D]  stage 3 (MFMA)
//  r  = sum_k softmax_k(ra)*know            [B,D]    online softmax on C-frags
// Precision: activations bf16(hi), weights bf16 hi+lo (2 MFMAs), fp32 accum.
// R10: launch_bounds(256,3) — R9's (256,4) forced VGPR 92->64 and spilled
//      Bf[] to scratch (WRITE_SIZE 1.5->336 MB, 5x regression). Cap 170
//      leaves the needed ~92 unspilled; LDS 34816 still allows 4 blocks/CU.

#define B_ 16
#define K_ 8192
#define D_ 128
#define CK 128                 // rows per workgroup (2 passes of SUB)
#define NCHUNK (K_ / CK)       // 64
#define SUB 64                 // rows per pass (LDS-resident)
#define NPASS (CK / SUB)       // 2
#define TRS 32                 // rows per row-tile
#define NTS (SUB / TRS)        // 2
#define LDP 136                // LDS row stride in bf16 elems (272B: 16B-mult, 2-way banks only)

typedef __attribute__((ext_vector_type(8))) short short8;
typedef __attribute__((ext_vector_type(4))) float f32x4;

__device__ __forceinline__ unsigned short f2bf(float x) {
  unsigned int u = __float_as_uint(x);
  u = (u + 0x7fffu + ((u >> 16) & 1u)) >> 16;   // RNE
  return (unsigned short)u;
}
__device__ __forceinline__ float bf2f(unsigned short h) {
  return __uint_as_float(((unsigned int)h) << 16);
}

// ---- prep: pack weights into MFMA B-frag order (bf16 hi/lo) + Im projection ----
// frag id F = (QQ*8 + nfrag)*2 + h ; QQ: 0-3 Wik, 4-11 Wid, 12-15 Wra.
// B-frag elem: lane l, j=0..7 -> B[k=32q+(l>>4)*8+j][col=16n+(l&15)]
__global__ void prep_kernel(const float* __restrict__ m_prev,
                            const float* __restrict__ Wim,
                            const float* __restrict__ bim,
                            const float* __restrict__ Wik,
                            const float* __restrict__ Wid,
                            const float* __restrict__ Wra,
                            unsigned short* __restrict__ packed,
                            float* __restrict__ Im) {
  const int blk = blockIdx.x;
  const int l = threadIdx.x;     // 0..63
  if (blk < 256) {
    const int F = blk;
    const int h = F & 1;
    const int n = (F >> 1) & 7;
    const int QQ = F >> 4;
    const float* W; int q;
    if (QQ < 4)       { W = Wik; q = QQ; }
    else if (QQ < 12) { W = Wid; q = QQ - 4; }
    else              { W = Wra; q = QQ - 12; }
    const int col = n * 16 + (l & 15);
    const int kb = q * 32 + (l >> 4) * 8;
    unsigned short* dst = packed + (size_t)F * 512 + l * 8;
#pragma unroll
    for (int j = 0; j < 8; ++j) {
      const float v = W[(kb + j) * D_ + col];
      const unsigned short hi = f2bf(v);
      dst[j] = h ? f2bf(v - bf2f(hi)) : hi;
    }
  } else {
    const int idx = blk - 256;          // 0..31
    const int b = idx >> 1;
    const int e = (idx & 1) * 64 + l;
    const float* mp = m_prev + b * D_;
    float acc = 0.f;
#pragma unroll 8
    for (int d = 0; d < D_; ++d) acc = fmaf(mp[d], Wim[d * D_ + e], acc);
    Im[b * D_ + e] = acc + bim[e];
  }
}

__global__ __launch_bounds__(256, 3) void readunit_main(
    const float* __restrict__ c_cur,
    const float* __restrict__ knowledge,
    const float* __restrict__ bik,
    const float* __restrict__ bid,
    const float* __restrict__ bra,
    const float* __restrict__ Im,
    const unsigned short* __restrict__ packed,
    float* __restrict__ partial) {
  __shared__ unsigned short know_h[SUB * LDP];  // 17408 B
  __shared__ unsigned short I_h[SUB * LDP];     // 17408 B (reused as cI)

  const int chunk = blockIdx.x;
  const int b = blockIdx.y;
  const int tid = threadIdx.x;
  const int lane = tid & 63;
  const int wn = tid >> 6;       // wave id = column-split 0..3 (cols 32*wn..+31)
  const int lr = lane & 15;
  const int lg = lane >> 4;

  float imv[2], cv[2], bikv[2], bidv[2], brav[2];
#pragma unroll
  for (int f = 0; f < 2; ++f) {
    const int col = wn * 32 + f * 16 + lr;
    imv[f]  = Im[b * D_ + col];
    cv[f]   = c_cur[b * D_ + col];
    bikv[f] = bik[col];
    bidv[f] = bid[col];
    brav[f] = bra[col];
  }

  short8 Bf[2][8][2];  // [nfrag][kchunk][hi/lo] weight fragments, per stage
  float sm[2] = {-1e30f, -1e30f}, sl[2] = {0.f, 0.f}, sacc[2] = {0.f, 0.f};

  for (int pass = 0; pass < NPASS; ++pass) {
    __syncthreads();   // previous pass's phase-3 readers done with know_h/I_h

    // ---- stage knowledge rows [pass*SUB, pass*SUB+64) as bf16 hi ----
    const float* gk = knowledge +
        ((size_t)b * K_ + (size_t)(chunk * CK + pass * SUB)) * D_;
#pragma unroll
    for (int i = 0; i < 8; ++i) {
      const int flat = tid + 256 * i;   // float4 slot in 64x128 tile
      const int row = flat >> 5;        // 32 float4 per row
      const int c4 = (flat & 31) * 4;
      const float4 v = *(const float4*)(gk + row * D_ + c4);
      ushort4 hv;
      hv.x = f2bf(v.x); hv.y = f2bf(v.y); hv.z = f2bf(v.z); hv.w = f2bf(v.w);
      *(ushort4*)(&know_h[row * LDP + c4]) = hv;
    }
    __syncthreads();

    // ---- phase 1: I = (know@Wik+bik)*Im -> I_h ----
#pragma unroll
    for (int q = 0; q < 4; ++q)
#pragma unroll
      for (int f = 0; f < 2; ++f)
#pragma unroll
        for (int h = 0; h < 2; ++h) {
          const int F = (q * 8 + (wn * 2 + f)) * 2 + h;
          Bf[f][q][h] = *(const short8*)(packed + (size_t)F * 512 + lane * 8);
        }
    for (int t = 0; t < NTS; ++t) {
      const int rb = t * TRS;
      f32x4 acc[2][2] = {};
#pragma unroll
      for (int q = 0; q < 4; ++q) {
        const short8 a0 = *(const short8*)(&know_h[(rb + lr) * LDP + q * 32 + lg * 8]);
        const short8 a1 = *(const short8*)(&know_h[(rb + 16 + lr) * LDP + q * 32 + lg * 8]);
#pragma unroll
        for (int f = 0; f < 2; ++f) {
          acc[0][f] = __builtin_amdgcn_mfma_f32_16x16x32_bf16(a0, Bf[f][q][0], acc[0][f], 0, 0, 0);
          acc[0][f] = __builtin_amdgcn_mfma_f32_16x16x32_bf16(a0, Bf[f][q][1], acc[0][f], 0, 0, 0);
          acc[1][f] = __builtin_amdgcn_mfma_f32_16x16x32_bf16(a1, Bf[f][q][0], acc[1][f], 0, 0, 0);
          acc[1][f] = __builtin_amdgcn_mfma_f32_16x16x32_bf16(a1, Bf[f][q][1], acc[1][f], 0, 0, 0);
        }
      }
#pragma unroll
      for (int m = 0; m < 2; ++m)
#pragma unroll
        for (int f = 0; f < 2; ++f) {
          const int col = wn * 32 + f * 16 + lr;
#pragma unroll
          for (int r = 0; r < 4; ++r) {
            const int row = rb + m * 16 + lg * 4 + r;
            I_h[row * LDP + col] = f2bf((acc[m][f][r] + bikv[f]) * imv[f]);
          }
        }
    }
    __syncthreads();

    // ---- phase 2: cI = c_cur*([I|know]@Wid+bid) -> overwrite I_h tile-wise ----
#pragma unroll
    for (int q = 0; q < 8; ++q)
#pragma unroll
      for (int f = 0; f < 2; ++f)
#pragma unroll
        for (int h = 0; h < 2; ++h) {
          const int F = ((4 + q) * 8 + (wn * 2 + f)) * 2 + h;
          Bf[f][q][h] = *(const short8*)(packed + (size_t)F * 512 + lane * 8);
        }
    for (int t = 0; t < NTS; ++t) {
      const int rb = t * TRS;
      f32x4 acc[2][2] = {};
#pragma unroll
      for (int q = 0; q < 8; ++q) {
        const unsigned short* src = (q < 4)
            ? &I_h[(rb + lr) * LDP + q * 32 + lg * 8]
            : &know_h[(rb + lr) * LDP + (q - 4) * 32 + lg * 8];
        const short8 a0 = *(const short8*)(src);
        const short8 a1 = *(const short8*)(src + 16 * LDP);
#pragma unroll
        for (int f = 0; f < 2; ++f) {
          acc[0][f] = __builtin_amdgcn_mfma_f32_16x16x32_bf16(a0, Bf[f][q][0], acc[0][f], 0, 0, 0);
          acc[0][f] = __builtin_amdgcn_mfma_f32_16x16x32_bf16(a0, Bf[f][q][1], acc[0][f], 0, 0, 0);
          acc[1][f] = __builtin_amdgcn_mfma_f32_16x16x32_bf16(a1, Bf[f][q][0], acc[1][f], 0, 0, 0);
          acc[1][f] = __builtin_amdgcn_mfma_f32_16x16x32_bf16(a1, Bf[f][q][1], acc[1][f], 0, 0, 0);
        }
      }
      __syncthreads();   // all waves finished reading tile t of I_h
#pragma unroll
      for (int m = 0; m < 2; ++m)
#pragma unroll
        for (int f = 0; f < 2; ++f) {
          const int col = wn * 32 + f * 16 + lr;
#pragma unroll
          for (int r = 0; r < 4; ++r) {
            const int row = rb + m * 16 + lg * 4 + r;
            I_h[row * LDP + col] = f2bf(cv[f] * (acc[m][f][r] + bidv[f]));
          }
        }
      // next tile reads disjoint rows; no barrier needed here
    }
    __syncthreads();

    // ---- phase 3: ra = cI@Wra+bra ; online softmax update ----
#pragma unroll
    for (int q = 0; q < 4; ++q)
#pragma unroll
      for (int f = 0; f < 2; ++f)
#pragma unroll
        for (int h = 0; h < 2; ++h) {
          const int F = ((12 + q) * 8 + (wn * 2 + f)) * 2 + h;
          Bf[f][q][h] = *(const short8*)(packed + (size_t)F * 512 + lane * 8);
        }
    for (int t = 0; t < NTS; ++t) {
      const int rb = t * TRS;
      f32x4 acc[2][2] = {};
#pragma unroll
      for (int q = 0; q < 4; ++q) {
        const short8 a0 = *(const short8*)(&I_h[(rb + lr) * LDP + q * 32 + lg * 8]);
        const short8 a1 = *(const short8*)(&I_h[(rb + 16 + lr) * LDP + q * 32 + lg * 8]);
#pragma unroll
        for (int f = 0; f < 2; ++f) {
          acc[0][f] = __builtin_amdgcn_mfma_f32_16x16x32_bf16(a0, Bf[f][q][0], acc[0][f], 0, 0, 0);
          acc[0][f] = __builtin_amdgcn_mfma_f32_16x16x32_bf16(a0, Bf[f][q][1], acc[0][f], 0, 0, 0);
          acc[1][f] = __builtin_amdgcn_mfma_f32_16x16x32_bf16(a1, Bf[f][q][0], acc[1][f], 0, 0, 0);
          acc[1][f] = __builtin_amdgcn_mfma_f32_16x16x32_bf16(a1, Bf[f][q][1], acc[1][f], 0, 0, 0);
        }
      }
#pragma unroll
      for (int f = 0; f < 2; ++f) {
        const int col = wn * 32 + f * 16 + lr;
        float v[8];
#pragma unroll
        for (int m = 0; m < 2; ++m)
#pragma unroll
          for (int r = 0; r < 4; ++r) v[m * 4 + r] = acc[m][f][r] + brav[f];
        float tmax = v[0];
#pragma unroll
        for (int i = 1; i < 8; ++i) tmax = fmaxf(tmax, v[i]);
        const float mnew = fmaxf(sm[f], tmax);
        const float scale = __expf(sm[f] - mnew);
        sl[f] *= scale;
        sacc[f] *= scale;
#pragma unroll
        for (int m = 0; m < 2; ++m)
#pragma unroll
          for (int r = 0; r < 4; ++r) {
            const int row = rb + m * 16 + lg * 4 + r;
            const float p = __expf(v[m * 4 + r] - mnew);
            sl[f] += p;
            sacc[f] = fmaf(p, bf2f(know_h[row * LDP + col]), sacc[f]);
          }
        sm[f] = mnew;
      }
    }
  }

  // ---- merge across the 4 lane-groups (rows), write chunk partial ----
#pragma unroll
  for (int f = 0; f < 2; ++f) {
#pragma unroll
    for (int s = 0; s < 2; ++s) {
      const int off = (s == 0) ? 16 : 32;
      const float om = __shfl_xor(sm[f], off);
      const float ol = __shfl_xor(sl[f], off);
      const float oa = __shfl_xor(sacc[f], off);
      const float mn = fmaxf(sm[f], om);
      const float e0 = __expf(sm[f] - mn), e1 = __expf(om - mn);
      sl[f] = sl[f] * e0 + ol * e1;
      sacc[f] = sacc[f] * e0 + oa * e1;
      sm[f] = mn;
    }
  }
  if (lg == 0) {
    float* p = partial + (size_t)(b * NCHUNK + chunk) * (3 * D_);
#pragma unroll
    for (int f = 0; f < 2; ++f) {
      const int col = wn * 32 + f * 16 + lr;
      p[col] = sm[f];
      p[D_ + col] = sl[f];
      p[2 * D_ + col] = sacc[f];
    }
  }
}

// 512 threads: 4 chunk-groups x 128 d. 16 serial merges + LDS tree merge.
__global__ void readunit_reduce(const float* __restrict__ partial,
                                float* __restrict__ out) {
  __shared__ float s_m[4][D_], s_l[4][D_], s_a[4][D_];
  const int b = blockIdx.x;
  const int tid = threadIdx.x;
  const int g = tid >> 7;        // 0..3
  const int d = tid & 127;
  float m = -1e30f, l = 0.f, a = 0.f;
  for (int c = g * 16; c < g * 16 + 16; ++c) {
    const float* p = partial + (size_t)(b * NCHUNK + c) * (3 * D_);
    const float mc = p[d], lc = p[D_ + d], ac = p[2 * D_ + d];
    const float mn = fmaxf(m, mc);
    const float s0 = __expf(m - mn), s1 = __expf(mc - mn);
    l = l * s0 + lc * s1;
    a = a * s0 + ac * s1;
    m = mn;
  }
  s_m[g][d] = m; s_l[g][d] = l; s_a[g][d] = a;
  __syncthreads();
  if (g == 0) {
#pragma unroll
    for (int i = 1; i < 4; ++i) {
      const float mc = s_m[i][d], lc = s_l[i][d], ac = s_a[i][d];
      const float mn = fmaxf(m, mc);
      const float s0 = __expf(m - mn), s1 = __expf(mc - mn);
      l = l * s0 + lc * s1;
      a = a * s0 + ac * s1;
      m = mn;
    }
    out[b * D_ + d] = a / l;
  }
}

extern "C" void kernel_launch(void* const* d_in, const int* in_sizes, int n_in,
                              void* d_out, int out_size, void* d_ws, size_t ws_size,
                              hipStream_t stream) {
  const float* c_cur = (const float*)d_in[0];
  const float* m_prev = (const float*)d_in[1];
  const float* knowledge = (const float*)d_in[2];
  const float* Wim = (const float*)d_in[3];
  const float* Wik = (const float*)d_in[4];
  const float* Wid = (const float*)d_in[5];
  const float* Wra = (const float*)d_in[6];
  const float* bim = (const float*)d_in[7];
  const float* bik = (const float*)d_in[8];
  const float* bid = (const float*)d_in[9];
  const float* bra = (const float*)d_in[10];
  float* out = (float*)d_out;

  float* Im = (float*)d_ws;                            // 2048 floats
  float* partial = Im + B_ * D_;                       // 16*64*384 floats (~1.5 MB)
  unsigned short* packed =
      (unsigned short*)(partial + (size_t)B_ * NCHUNK * 3 * D_);  // 256 KB

  prep_kernel<<<288, 64, 0, stream>>>(m_prev, Wim, bim, Wik, Wid, Wra, packed, Im);
  readunit_main<<<dim3(NCHUNK, B_), 256, 0, stream>>>(
      c_cur, knowledge, bik, bid, bra, Im, packed, partial);
  readunit_reduce<<<B_, 512, 0, stream>>>(partial, out);
}

// Round 11
// 239.347 us; speedup vs baseline: 1.4470x; 1.4470x over previous
//
#include <hip/hip_runtime.h>
#include <cmath>

// ReadUnit, MFMA version. B=16, K=8192, D=128.
//  Im = m_prev@Wim+bim                      [B,D]    (prep kernel)
//  I  = (know@Wik+bik)*Im                   [B,K,D]  stage 1 (MFMA)
//  cI = c_cur*([I|know]@Wid+bid)            [B,K,D]  stage 2 (MFMA)
//  ra = cI@Wra+bra                          [B,K,D]  stage 3 (MFMA)
//  r  = sum_k softmax_k(ra)*know            [B,D]    online softmax on C-frags
// Precision: activations bf16(hi), weights bf16 hi+lo (2 MFMAs), fp32 accum.
// R11: launch_bounds back to (256,2) — measured: (256,3)/(256,4) make the
//      allocator split the unified VGPR/AGPR budget to ~cap/2 arch VGPRs
//      (84/64), spilling Bf[] (~333 MB scratch traffic, 5x). (256,2) is the
//      proven spill-free config (R8: VGPR 92, 1.5 MB writes). Occupancy now
//      comes from LDS: 34816 B -> 4 blocks/CU vs R8's 2.

#define B_ 16
#define K_ 8192
#define D_ 128
#define CK 128                 // rows per workgroup (2 passes of SUB)
#define NCHUNK (K_ / CK)       // 64
#define SUB 64                 // rows per pass (LDS-resident)
#define NPASS (CK / SUB)       // 2
#define TRS 32                 // rows per row-tile
#define NTS (SUB / TRS)        // 2
#define LDP 136                // LDS row stride in bf16 elems (272B: 16B-mult, 2-way banks only)

typedef __attribute__((ext_vector_type(8))) short short8;
typedef __attribute__((ext_vector_type(4))) float f32x4;

__device__ __forceinline__ unsigned short f2bf(float x) {
  unsigned int u = __float_as_uint(x);
  u = (u + 0x7fffu + ((u >> 16) & 1u)) >> 16;   // RNE
  return (unsigned short)u;
}
__device__ __forceinline__ float bf2f(unsigned short h) {
  return __uint_as_float(((unsigned int)h) << 16);
}

// ---- prep: pack weights into MFMA B-frag order (bf16 hi/lo) + Im projection ----
// frag id F = (QQ*8 + nfrag)*2 + h ; QQ: 0-3 Wik, 4-11 Wid, 12-15 Wra.
// B-frag elem: lane l, j=0..7 -> B[k=32q+(l>>4)*8+j][col=16n+(l&15)]
__global__ void prep_kernel(const float* __restrict__ m_prev,
                            const float* __restrict__ Wim,
                            const float* __restrict__ bim,
                            const float* __restrict__ Wik,
                            const float* __restrict__ Wid,
                            const float* __restrict__ Wra,
                            unsigned short* __restrict__ packed,
                            float* __restrict__ Im) {
  const int blk = blockIdx.x;
  const int l = threadIdx.x;     // 0..63
  if (blk < 256) {
    const int F = blk;
    const int h = F & 1;
    const int n = (F >> 1) & 7;
    const int QQ = F >> 4;
    const float* W; int q;
    if (QQ < 4)       { W = Wik; q = QQ; }
    else if (QQ < 12) { W = Wid; q = QQ - 4; }
    else              { W = Wra; q = QQ - 12; }
    const int col = n * 16 + (l & 15);
    const int kb = q * 32 + (l >> 4) * 8;
    unsigned short* dst = packed + (size_t)F * 512 + l * 8;
#pragma unroll
    for (int j = 0; j < 8; ++j) {
      const float v = W[(kb + j) * D_ + col];
      const unsigned short hi = f2bf(v);
      dst[j] = h ? f2bf(v - bf2f(hi)) : hi;
    }
  } else {
    const int idx = blk - 256;          // 0..31
    const int b = idx >> 1;
    const int e = (idx & 1) * 64 + l;
    const float* mp = m_prev + b * D_;
    float acc = 0.f;
#pragma unroll 8
    for (int d = 0; d < D_; ++d) acc = fmaf(mp[d], Wim[d * D_ + e], acc);
    Im[b * D_ + e] = acc + bim[e];
  }
}

__global__ __launch_bounds__(256, 2) void readunit_main(
    const float* __restrict__ c_cur,
    const float* __restrict__ knowledge,
    const float* __restrict__ bik,
    const float* __restrict__ bid,
    const float* __restrict__ bra,
    const float* __restrict__ Im,
    const unsigned short* __restrict__ packed,
    float* __restrict__ partial) {
  __shared__ unsigned short know_h[SUB * LDP];  // 17408 B
  __shared__ unsigned short I_h[SUB * LDP];     // 17408 B (reused as cI)

  const int chunk = blockIdx.x;
  const int b = blockIdx.y;
  const int tid = threadIdx.x;
  const int lane = tid & 63;
  const int wn = tid >> 6;       // wave id = column-split 0..3 (cols 32*wn..+31)
  const int lr = lane & 15;
  const int lg = lane >> 4;

  float imv[2], cv[2], bikv[2], bidv[2], brav[2];
#pragma unroll
  for (int f = 0; f < 2; ++f) {
    const int col = wn * 32 + f * 16 + lr;
    imv[f]  = Im[b * D_ + col];
    cv[f]   = c_cur[b * D_ + col];
    bikv[f] = bik[col];
    bidv[f] = bid[col];
    brav[f] = bra[col];
  }

  short8 Bf[2][8][2];  // [nfrag][kchunk][hi/lo] weight fragments, per stage
  float sm[2] = {-1e30f, -1e30f}, sl[2] = {0.f, 0.f}, sacc[2] = {0.f, 0.f};

  for (int pass = 0; pass < NPASS; ++pass) {
    __syncthreads();   // previous pass's phase-3 readers done with know_h/I_h

    // ---- stage knowledge rows [pass*SUB, pass*SUB+64) as bf16 hi ----
    const float* gk = knowledge +
        ((size_t)b * K_ + (size_t)(chunk * CK + pass * SUB)) * D_;
#pragma unroll
    for (int i = 0; i < 8; ++i) {
      const int flat = tid + 256 * i;   // float4 slot in 64x128 tile
      const int row = flat >> 5;        // 32 float4 per row
      const int c4 = (flat & 31) * 4;
      const float4 v = *(const float4*)(gk + row * D_ + c4);
      ushort4 hv;
      hv.x = f2bf(v.x); hv.y = f2bf(v.y); hv.z = f2bf(v.z); hv.w = f2bf(v.w);
      *(ushort4*)(&know_h[row * LDP + c4]) = hv;
    }
    __syncthreads();

    // ---- phase 1: I = (know@Wik+bik)*Im -> I_h ----
#pragma unroll
    for (int q = 0; q < 4; ++q)
#pragma unroll
      for (int f = 0; f < 2; ++f)
#pragma unroll
        for (int h = 0; h < 2; ++h) {
          const int F = (q * 8 + (wn * 2 + f)) * 2 + h;
          Bf[f][q][h] = *(const short8*)(packed + (size_t)F * 512 + lane * 8);
        }
    for (int t = 0; t < NTS; ++t) {
      const int rb = t * TRS;
      f32x4 acc[2][2] = {};
#pragma unroll
      for (int q = 0; q < 4; ++q) {
        const short8 a0 = *(const short8*)(&know_h[(rb + lr) * LDP + q * 32 + lg * 8]);
        const short8 a1 = *(const short8*)(&know_h[(rb + 16 + lr) * LDP + q * 32 + lg * 8]);
#pragma unroll
        for (int f = 0; f < 2; ++f) {
          acc[0][f] = __builtin_amdgcn_mfma_f32_16x16x32_bf16(a0, Bf[f][q][0], acc[0][f], 0, 0, 0);
          acc[0][f] = __builtin_amdgcn_mfma_f32_16x16x32_bf16(a0, Bf[f][q][1], acc[0][f], 0, 0, 0);
          acc[1][f] = __builtin_amdgcn_mfma_f32_16x16x32_bf16(a1, Bf[f][q][0], acc[1][f], 0, 0, 0);
          acc[1][f] = __builtin_amdgcn_mfma_f32_16x16x32_bf16(a1, Bf[f][q][1], acc[1][f], 0, 0, 0);
        }
      }
#pragma unroll
      for (int m = 0; m < 2; ++m)
#pragma unroll
        for (int f = 0; f < 2; ++f) {
          const int col = wn * 32 + f * 16 + lr;
#pragma unroll
          for (int r = 0; r < 4; ++r) {
            const int row = rb + m * 16 + lg * 4 + r;
            I_h[row * LDP + col] = f2bf((acc[m][f][r] + bikv[f]) * imv[f]);
          }
        }
    }
    __syncthreads();

    // ---- phase 2: cI = c_cur*([I|know]@Wid+bid) -> overwrite I_h tile-wise ----
#pragma unroll
    for (int q = 0; q < 8; ++q)
#pragma unroll
      for (int f = 0; f < 2; ++f)
#pragma unroll
        for (int h = 0; h < 2; ++h) {
          const int F = ((4 + q) * 8 + (wn * 2 + f)) * 2 + h;
          Bf[f][q][h] = *(const short8*)(packed + (size_t)F * 512 + lane * 8);
        }
    for (int t = 0; t < NTS; ++t) {
      const int rb = t * TRS;
      f32x4 acc[2][2] = {};
#pragma unroll
      for (int q = 0; q < 8; ++q) {
        const unsigned short* src = (q < 4)
            ? &I_h[(rb + lr) * LDP + q * 32 + lg * 8]
            : &know_h[(rb + lr) * LDP + (q - 4) * 32 + lg * 8];
        const short8 a0 = *(const short8*)(src);
        const short8 a1 = *(const short8*)(src + 16 * LDP);
#pragma unroll
        for (int f = 0; f < 2; ++f) {
          acc[0][f] = __builtin_amdgcn_mfma_f32_16x16x32_bf16(a0, Bf[f][q][0], acc[0][f], 0, 0, 0);
          acc[0][f] = __builtin_amdgcn_mfma_f32_16x16x32_bf16(a0, Bf[f][q][1], acc[0][f], 0, 0, 0);
          acc[1][f] = __builtin_amdgcn_mfma_f32_16x16x32_bf16(a1, Bf[f][q][0], acc[1][f], 0, 0, 0);
          acc[1][f] = __builtin_amdgcn_mfma_f32_16x16x32_bf16(a1, Bf[f][q][1], acc[1][f], 0, 0, 0);
        }
      }
      __syncthreads();   // all waves finished reading tile t of I_h
#pragma unroll
      for (int m = 0; m < 2; ++m)
#pragma unroll
        for (int f = 0; f < 2; ++f) {
          const int col = wn * 32 + f * 16 + lr;
#pragma unroll
          for (int r = 0; r < 4; ++r) {
            const int row = rb + m * 16 + lg * 4 + r;
            I_h[row * LDP + col] = f2bf(cv[f] * (acc[m][f][r] + bidv[f]));
          }
        }
      // next tile reads disjoint rows; no barrier needed here
    }
    __syncthreads();

    // ---- phase 3: ra = cI@Wra+bra ; online softmax update ----
#pragma unroll
    for (int q = 0; q < 4; ++q)
#pragma unroll
      for (int f = 0; f < 2; ++f)
#pragma unroll
        for (int h = 0; h < 2; ++h) {
          const int F = ((12 + q) * 8 + (wn * 2 + f)) * 2 + h;
          Bf[f][q][h] = *(const short8*)(packed + (size_t)F * 512 + lane * 8);
        }
    for (int t = 0; t < NTS; ++t) {
      const int rb = t * TRS;
      f32x4 acc[2][2] = {};
#pragma unroll
      for (int q = 0; q < 4; ++q) {
        const short8 a0 = *(const short8*)(&I_h[(rb + lr) * LDP + q * 32 + lg * 8]);
        const short8 a1 = *(const short8*)(&I_h[(rb + 16 + lr) * LDP + q * 32 + lg * 8]);
#pragma unroll
        for (int f = 0; f < 2; ++f) {
          acc[0][f] = __builtin_amdgcn_mfma_f32_16x16x32_bf16(a0, Bf[f][q][0], acc[0][f], 0, 0, 0);
          acc[0][f] = __builtin_amdgcn_mfma_f32_16x16x32_bf16(a0, Bf[f][q][1], acc[0][f], 0, 0, 0);
          acc[1][f] = __builtin_amdgcn_mfma_f32_16x16x32_bf16(a1, Bf[f][q][0], acc[1][f], 0, 0, 0);
          acc[1][f] = __builtin_amdgcn_mfma_f32_16x16x32_bf16(a1, Bf[f][q][1], acc[1][f], 0, 0, 0);
        }
      }
#pragma unroll
      for (int f = 0; f < 2; ++f) {
        const int col = wn * 32 + f * 16 + lr;
        float v[8];
#pragma unroll
        for (int m = 0; m < 2; ++m)
#pragma unroll
          for (int r = 0; r < 4; ++r) v[m * 4 + r] = acc[m][f][r] + brav[f];
        float tmax = v[0];
#pragma unroll
        for (int i = 1; i < 8; ++i) tmax = fmaxf(tmax, v[i]);
        const float mnew = fmaxf(sm[f], tmax);
        const float scale = __expf(sm[f] - mnew);
        sl[f] *= scale;
        sacc[f] *= scale;
#pragma unroll
        for (int m = 0; m < 2; ++m)
#pragma unroll
          for (int r = 0; r < 4; ++r) {
            const int row = rb + m * 16 + lg * 4 + r;
            const float p = __expf(v[m * 4 + r] - mnew);
            sl[f] += p;
            sacc[f] = fmaf(p, bf2f(know_h[row * LDP + col]), sacc[f]);
          }
        sm[f] = mnew;
      }
    }
  }

  // ---- merge across the 4 lane-groups (rows), write chunk partial ----
#pragma unroll
  for (int f = 0; f < 2; ++f) {
#pragma unroll
    for (int s = 0; s < 2; ++s) {
      const int off = (s == 0) ? 16 : 32;
      const float om = __shfl_xor(sm[f], off);
      const float ol = __shfl_xor(sl[f], off);
      const float oa = __shfl_xor(sacc[f], off);
      const float mn = fmaxf(sm[f], om);
      const float e0 = __expf(sm[f] - mn), e1 = __expf(om - mn);
      sl[f] = sl[f] * e0 + ol * e1;
      sacc[f] = sacc[f] * e0 + oa * e1;
      sm[f] = mn;
    }
  }
  if (lg == 0) {
    float* p = partial + (size_t)(b * NCHUNK + chunk) * (3 * D_);
#pragma unroll
    for (int f = 0; f < 2; ++f) {
      const int col = wn * 32 + f * 16 + lr;
      p[col] = sm[f];
      p[D_ + col] = sl[f];
      p[2 * D_ + col] = sacc[f];
    }
  }
}

// 512 threads: 4 chunk-groups x 128 d. 16 serial merges + LDS tree merge.
__global__ void readunit_reduce(const float* __restrict__ partial,
                                float* __restrict__ out) {
  __shared__ float s_m[4][D_], s_l[4][D_], s_a[4][D_];
  const int b = blockIdx.x;
  const int tid = threadIdx.x;
  const int g = tid >> 7;        // 0..3
  const int d = tid & 127;
  float m = -1e30f, l = 0.f, a = 0.f;
  for (int c = g * 16; c < g * 16 + 16; ++c) {
    const float* p = partial + (size_t)(b * NCHUNK + c) * (3 * D_);
    const float mc = p[d], lc = p[D_ + d], ac = p[2 * D_ + d];
    const float mn = fmaxf(m, mc);
    const float s0 = __expf(m - mn), s1 = __expf(mc - mn);
    l = l * s0 + lc * s1;
    a = a * s0 + ac * s1;
    m = mn;
  }
  s_m[g][d] = m; s_l[g][d] = l; s_a[g][d] = a;
  __syncthreads();
  if (g == 0) {
#pragma unroll
    for (int i = 1; i < 4; ++i) {
      const float mc = s_m[i][d], lc = s_l[i][d], ac = s_a[i][d];
      const float mn = fmaxf(m, mc);
      const float s0 = __expf(m - mn), s1 = __expf(mc - mn);
      l = l * s0 + lc * s1;
      a = a * s0 + ac * s1;
      m = mn;
    }
    out[b * D_ + d] = a / l;
  }
}

extern "C" void kernel_launch(void* const* d_in, const int* in_sizes, int n_in,
                              void* d_out, int out_size, void* d_ws, size_t ws_size,
                              hipStream_t stream) {
  const float* c_cur = (const float*)d_in[0];
  const float* m_prev = (const float*)d_in[1];
  const float* knowledge = (const float*)d_in[2];
  const float* Wim = (const float*)d_in[3];
  const float* Wik = (const float*)d_in[4];
  const float* Wid = (const float*)d_in[5];
  const float* Wra = (const float*)d_in[6];
  const float* bim = (const float*)d_in[7];
  const float* bik = (const float*)d_in[8];
  const float* bid = (const float*)d_in[9];
  const float* bra = (const float*)d_in[10];
  float* out = (float*)d_out;

  float* Im = (float*)d_ws;                            // 2048 floats
  float* partial = Im + B_ * D_;                       // 16*64*384 floats (~1.5 MB)
  unsigned short* packed =
      (unsigned short*)(partial + (size_t)B_ * NCHUNK * 3 * D_);  // 256 KB

  prep_kernel<<<288, 64, 0, stream>>>(m_prev, Wim, bim, Wik, Wid, Wra, packed, Im);
  readunit_main<<<dim3(NCHUNK, B_), 256, 0, stream>>>(
      c_cur, knowledge, bik, bid, bra, Im, packed, partial);
  readunit_reduce<<<B_, 512, 0, stream>>>(partial, out);
}